// Round 8
// baseline (156.559 us; speedup 1.0000x reference)
//
#include <hip/hip_runtime.h>
#include <hip/hip_fp16.h>
#include <math.h>

// sigAct: u0 = sigmoid(-(lam_b*conv(1-2x))/eps); 5 damped updates.
// conv = separable 17-tap Gaussian (sigma=2) in LDS, f32 accumulation.
// Round-8: round-5 structure (1 tile/block, 6 blocks/CU) +
//  (a) entry prefetch of epilogue xl/c into regs (issue-early/consume-late;
//      round-5 interleaved xl loads with aliasing stores -> serialized tail),
//  (b) vpass = 2 columns/thread via half2 b32 LDS reads (48->32 LDS instr),
//      half2/float2 global stores,
//  (c) u-halo prefetched to regs then staged (loads batch at entry).
// Round-7 lesson: never pay occupancy for prefetch (6 blocks/CU kept).

#define TILE 64
#define RAD  8
#define IN_W 80
#define HW   512
#define NIMG 24
#define NPIX ((size_t)HW * HW * NIMG)

// 1D normalized Gaussian, sigma=2, 17 taps: exp(-(k-8)^2/8) / 5.0131684
__device__ __constant__ const float GWc[17] = {
    6.6916e-05f, 4.3635e-04f, 2.2159612e-03f, 8.7643070e-03f,
    2.6995958e-02f, 6.4759932e-02f, 1.2098751e-01f, 1.7603572e-01f,
    1.9947466e-01f,
    1.7603572e-01f, 1.2098751e-01f, 6.4759932e-02f, 2.6995958e-02f,
    8.7643070e-03f, 2.2159612e-03f, 4.3635e-04f, 6.6916e-05f
};

struct alignas(8)  H4 { __half2 a, b; };
struct alignas(16) H8 { __half2 a, b, c, d; };

// sigmoid(-z) = 1/(1+exp(z)); inf->0, -inf->1.
__device__ __forceinline__ float inv1pexp(float z) {
    return __builtin_amdgcn_rcpf(1.0f + __expf(z));
}

// ---- prefetch u halo (half) into regs ----
__device__ __forceinline__ void prefetch_h(const __half* ub, H8* p,
                                           int t, int row0, int col0) {
#pragma unroll
    for (int i = 0; i < 4; ++i) {
        int q = t + i * 256;
        int r = q / 10, c8 = (q - r * 10) * 8;
        int gr = row0 + r - RAD, gc = col0 + c8 - RAD;
        if (q < 800 && gr >= 0 && gr < HW && gc >= 0 && gc < HW)
            p[i] = *reinterpret_cast<const H8*>(&ub[(size_t)gr * HW + gc]);
    }
}

// ---- write prefetched half tile to LDS as f = 1-2u (zero-pad OOB) ----
__device__ __forceinline__ void wstage_h(const H8* pp, __half* sIn,
                                         int t, int row0, int col0) {
#pragma unroll
    for (int i = 0; i < 4; ++i) {
        int q = t + i * 256;
        if (q < 800) {
            int r = q / 10, c8 = (q - r * 10) * 8;
            int gr = row0 + r - RAD, gc = col0 + c8 - RAD;
            H8 v;
            if (gr >= 0 && gr < HW && gc >= 0 && gc < HW) {
                const __half2 one2 = __floats2half2_rn(1.f, 1.f);
                v = pp[i];
                v.a = __hsub2(one2, __hadd2(v.a, v.a));
                v.b = __hsub2(one2, __hadd2(v.b, v.b));
                v.c = __hsub2(one2, __hadd2(v.c, v.c));
                v.d = __hsub2(one2, __hadd2(v.d, v.d));
            } else {
                v.a = __floats2half2_rn(0.f, 0.f);
                v.b = v.a; v.c = v.a; v.d = v.a;
            }
            *reinterpret_cast<H8*>(&sIn[r * IN_W + c8]) = v;
        }
    }
}

// ---- prefetch x halo (f32) into regs ----
__device__ __forceinline__ void prefetch_f(const float* xb, float4* q4,
                                           int t, int row0, int col0) {
#pragma unroll
    for (int i = 0; i < 7; ++i) {
        int q = t + i * 256;
        int r = q / 20, c4 = (q - r * 20) * 4;
        int gr = row0 + r - RAD, gc = col0 + c4 - RAD;
        if (q < 1600 && gr >= 0 && gr < HW && gc >= 0 && gc < HW)
            q4[i] = *reinterpret_cast<const float4*>(&xb[(size_t)gr * HW + gc]);
    }
}

// ---- write prefetched f32 tile to LDS as f = 1-2x (zero-pad OOB) ----
__device__ __forceinline__ void wstage_f(const float4* qq, __half* sIn,
                                         int t, int row0, int col0) {
#pragma unroll
    for (int i = 0; i < 7; ++i) {
        int q = t + i * 256;
        if (q < 1600) {
            int r = q / 20, c4 = (q - r * 20) * 4;
            int gr = row0 + r - RAD, gc = col0 + c4 - RAD;
            H4 o;
            if (gr >= 0 && gr < HW && gc >= 0 && gc < HW) {
                float4 v = qq[i];
                o.a = __floats2half2_rn(1.f - 2.f * v.x, 1.f - 2.f * v.y);
                o.b = __floats2half2_rn(1.f - 2.f * v.z, 1.f - 2.f * v.w);
            } else { o.a = __floats2half2_rn(0.f, 0.f); o.b = o.a; }
            *reinterpret_cast<H4*>(&sIn[r * IN_W + c4]) = o;
        }
    }
}

// ---- horizontal 17-tap pass: sIn[80][80] -> sTmp[80][64] ----
__device__ __forceinline__ void hpass(const __half* sIn, __half* sTmp, int t) {
#pragma unroll
    for (int i = 0; i < 5; ++i) {
        int gq = t + i * 256;              // 1280 groups: 80 rows x 16
        int r  = gq >> 4;
        int cp = (gq & 15) * 4;
        const __half* wp = &sIn[r * IN_W + cp];
        float w[20];
#pragma unroll
        for (int j = 0; j < 5; ++j) {      // 5 x ds_read_b64
            H4 h = *reinterpret_cast<const H4*>(wp + j * 4);
            float2 f0 = __half22float2(h.a);
            float2 f1 = __half22float2(h.b);
            w[j*4+0] = f0.x; w[j*4+1] = f0.y;
            w[j*4+2] = f1.x; w[j*4+3] = f1.y;
        }
        float a0 = 0.f, a1 = 0.f, a2 = 0.f, a3 = 0.f;
#pragma unroll
        for (int k = 0; k < 17; ++k) {
            float g = GWc[k];
            a0 += g * w[k];     a1 += g * w[k + 1];
            a2 += g * w[k + 2]; a3 += g * w[k + 3];
        }
        H4 o; o.a = __floats2half2_rn(a0, a1); o.b = __floats2half2_rn(a2, a3);
        *reinterpret_cast<H4*>(&sTmp[r * TILE + cp]) = o;
    }
}

template<int MODE> // 0=INIT 1=MID 2=FINAL
__global__ __launch_bounds__(256, 6) void sig_step(
    const float* __restrict__ xg, const float* __restrict__ cgl,
    const __half* __restrict__ uin, __half2* __restrict__ xl,
    void* __restrict__ uout)
{
    __shared__ __half sIn [IN_W * IN_W];   // 12.8 KB
    __shared__ __half sTmp[IN_W * TILE];   // 10.2 KB

    const int t    = threadIdx.x;
    const int img  = blockIdx.z;
    const int row0 = blockIdx.y * TILE;
    const int col0 = blockIdx.x * TILE;
    const size_t ibase = (size_t)img * HW * HW;

    // 2-col vpass ownership: cols {cc2,cc2+1}, rows [rg2*8, rg2*8+8)
    const int cc2 = (t & 31) * 2;
    const int rg2 = t >> 5;
    const size_t pb = ibase + (size_t)(row0 + rg2 * 8) * HW + (col0 + cc2);

    // ===== entry: issue ALL global loads (consume-late) =====
    float4 q4[7];  H8 ph[4];
    float2 cp[8];  H4 xp[8];
    if constexpr (MODE == 0) {
        prefetch_f(xg + ibase, q4, t, row0, col0);
#pragma unroll
        for (int m = 0; m < 8; ++m)
            cp[m] = *reinterpret_cast<const float2*>(&cgl[pb + (size_t)m * HW]);
    } else {
        prefetch_h(uin + ibase, ph, t, row0, col0);
#pragma unroll
        for (int m = 0; m < 8; ++m)     // xl may alias d_out: read before stores
            xp[m] = *reinterpret_cast<const H4*>(&xl[pb + (size_t)m * HW]);
    }

    // ===== stage -> hpass =====
    if constexpr (MODE == 0) wstage_f(q4, sIn, t, row0, col0);
    else                     wstage_h(ph, sIn, t, row0, col0);
    __syncthreads();
    hpass(sIn, sTmp, t);
    __syncthreads();

    // ===== vpass: 2 cols x 8 rows per thread, b32 LDS reads =====
    float w0[24], w1[24];
#pragma unroll
    for (int j = 0; j < 24; ++j) {
        __half2 h = *reinterpret_cast<const __half2*>(
            &sTmp[(rg2 * 8 + j) * TILE + cc2]);
        float2 f = __half22float2(h);
        w0[j] = f.x; w1[j] = f.y;
    }

#pragma unroll
    for (int m = 0; m < 8; ++m) {
        float a0 = 0.f, a1 = 0.f;
#pragma unroll
        for (int k = 0; k < 17; ++k) {
            float g = GWc[k];
            a0 += g * w0[m + k]; a1 += g * w1[m + k];
        }
        size_t gidx = pb + (size_t)m * HW;
        // sIn holds f=1-2u -> u=(1-f)/2 (INIT: u==x, same quantization as xl)
        __half2 hu = *reinterpret_cast<const __half2*>(
            &sIn[(rg2 * 8 + m + RAD) * IN_W + (cc2 + RAD)]);
        float2 fu = __half22float2(hu);
        float up0 = 0.5f * (1.f - fu.x), up1 = 0.5f * (1.f - fu.y);

        if constexpr (MODE == 0) {
            float lam0 = 100.f * inv1pexp(-10.f * cp[m].x);
            float lam1 = 100.f * inv1pexp(-10.f * cp[m].y);
            H4 o; o.a = __floats2half2_rn(up0, lam0);
                  o.b = __floats2half2_rn(up1, lam1);
            *reinterpret_cast<H4*>(&xl[gidx]) = o;
            *reinterpret_cast<__half2*>(&((__half*)uout)[gidx]) =
                __floats2half2_rn(inv1pexp(lam0 * a0 * 0.1f),
                                  inv1pexp(lam1 * a1 * 0.1f));
        } else {
            float2 p0 = __half22float2(xp[m].a);   // (x0, lam0)
            float2 p1 = __half22float2(xp[m].b);   // (x1, lam1)
            float t0 = (up0 - p0.x) * 10.f + p0.y * a0;
            float t1 = (up1 - p1.x) * 10.f + p1.y * a1;
            float r0 = 0.5f * up0 + 0.5f * inv1pexp(t0 * 0.1f);
            float r1 = 0.5f * up1 + 0.5f * inv1pexp(t1 * 0.1f);
            if constexpr (MODE == 2) {
                float2 o = make_float2(r0, r1);
                *reinterpret_cast<float2*>(&((float*)uout)[gidx]) = o;
            } else {
                *reinterpret_cast<__half2*>(&((__half*)uout)[gidx]) =
                    __floats2half2_rn(r0, r1);
            }
        }
    }
}

extern "C" void kernel_launch(void* const* d_in, const int* in_sizes, int n_in,
                              void* d_out, int out_size, void* d_ws, size_t ws_size,
                              hipStream_t stream) {
    const float* x = (const float*)d_in[0];
    const float* c = (const float*)d_in[1];

    __half* u0 = (__half*)d_ws;          // NPIX halfs = 12.6 MB
    __half* u1 = u0 + NPIX;              // 12.6 MB
    __half2* xl = (ws_size >= NPIX * 8)
        ? (__half2*)((char*)d_ws + NPIX * 4)
        : (__half2*)d_out;               // safe: epilogue preloads before store

    dim3 grid(HW / TILE, HW / TILE, NIMG);   // 8 x 8 x 24
    dim3 block(256);
    sig_step<0><<<grid, block, 0, stream>>>(x, c, nullptr, xl, u0);
    sig_step<1><<<grid, block, 0, stream>>>(x, c, u0, xl, u1);
    sig_step<1><<<grid, block, 0, stream>>>(x, c, u1, xl, u0);
    sig_step<1><<<grid, block, 0, stream>>>(x, c, u0, xl, u1);
    sig_step<1><<<grid, block, 0, stream>>>(x, c, u1, xl, u0);
    sig_step<2><<<grid, block, 0, stream>>>(x, c, u0, xl, d_out);
}

// Round 9
// 116.570 us; speedup vs baseline: 1.3430x; 1.3430x over previous
//
#include <hip/hip_runtime.h>
#include <hip/hip_fp16.h>
#include <math.h>

// sigAct: u0 = sigmoid(-(lam_b*conv(1-2x))/eps); 5 damped updates.
// conv = separable 17-tap Gaussian (sigma=2), f32 accumulation.
// Round-9: NO input staging. h-pass reads its 24-col window directly from
// global (3xH8 / 6xfloat4, overlapping chunks are L2/L3-hot), writes 8
// outputs to sTmp (only LDS buffer, 10.2 KB). ONE barrier. vpass = round-5
// verbatim (win[32] u16 reads, 1 col x 16 rows). u_prev/x/xl read from
// global in epilogue. 6 launches, fp16 u ping-pong, xl=(x,lam) half2 in ws.
// Lessons: r7/r8 = never pay registers/occupancy for prefetch; r6 = no
// grid.sync (XCD L2 flush storm). Keep VGPR lean, 6 blocks/CU.

#define TILE 64
#define RAD  8
#define HW   512
#define NIMG 24
#define NPIX ((size_t)HW * HW * NIMG)

// 1D normalized Gaussian, sigma=2, 17 taps: exp(-(k-8)^2/8) / 5.0131684
__device__ __constant__ const float GWc[17] = {
    6.6916e-05f, 4.3635e-04f, 2.2159612e-03f, 8.7643070e-03f,
    2.6995958e-02f, 6.4759932e-02f, 1.2098751e-01f, 1.7603572e-01f,
    1.9947466e-01f,
    1.7603572e-01f, 1.2098751e-01f, 6.4759932e-02f, 2.6995958e-02f,
    8.7643070e-03f, 2.2159612e-03f, 4.3635e-04f, 6.6916e-05f
};

struct alignas(8)  H4 { __half2 a, b; };
struct alignas(16) H8 { __half2 a, b, c, d; };

// sigmoid(-z) = 1/(1+exp(z)); inf->0, -inf->1.
__device__ __forceinline__ float inv1pexp(float z) {
    return __builtin_amdgcn_rcpf(1.0f + __expf(z));
}

template<int MODE> // 0=INIT 1=MID 2=FINAL
__global__ __launch_bounds__(256, 6) void sig_step(
    const float* __restrict__ xg, const float* __restrict__ cgl,
    const __half* __restrict__ uin, __half2* __restrict__ xl,
    void* __restrict__ uout)
{
    __shared__ __half sTmp[80 * TILE];   // h-pass output, 10.2 KB (only LDS)

    const int t    = threadIdx.x;
    const int img  = blockIdx.z;
    const int row0 = blockIdx.y * TILE;
    const int col0 = blockIdx.x * TILE;
    const size_t ibase = (size_t)img * HW * HW;

    // ===== h-pass: 640 units, each = (halo row r, 8-col group ci) =====
    // unit reads input cols [col0+8ci-8, col0+8ci+16) from GLOBAL, writes
    // 8 half outputs to sTmp[r][8ci..8ci+8). Zero-pad OOB (SAME conv).
#pragma unroll
    for (int i = 0; i < 3; ++i) {
        int q = t + i * 256;
        if (q < 640) {
            int r  = q >> 3;               // halo row 0..79
            int ci = q & 7;                // col group 0..7
            int gr = row0 + r - RAD;
            float w[24];
#pragma unroll
            for (int j = 0; j < 24; ++j) w[j] = 0.f;
            if (gr >= 0 && gr < HW) {
                int gc0 = col0 + ci * 8 - RAD;
                if constexpr (MODE == 0) {
                    const float* xb = xg + ibase + (size_t)gr * HW;
#pragma unroll
                    for (int j = 0; j < 6; ++j) {
                        int s = gc0 + 4 * j;
                        if (s >= 0 && s <= HW - 4) {
                            float4 v = *reinterpret_cast<const float4*>(&xb[s]);
                            w[4*j+0] = 1.f - 2.f * v.x;
                            w[4*j+1] = 1.f - 2.f * v.y;
                            w[4*j+2] = 1.f - 2.f * v.z;
                            w[4*j+3] = 1.f - 2.f * v.w;
                        }
                    }
                } else {
                    const __half* ub = uin + ibase + (size_t)gr * HW;
#pragma unroll
                    for (int j = 0; j < 3; ++j) {
                        int s = gc0 + 8 * j;
                        if (s >= 0 && s <= HW - 8) {
                            H8 v = *reinterpret_cast<const H8*>(&ub[s]);
                            float2 f0 = __half22float2(v.a);
                            float2 f1 = __half22float2(v.b);
                            float2 f2 = __half22float2(v.c);
                            float2 f3 = __half22float2(v.d);
                            w[8*j+0] = 1.f - 2.f * f0.x;
                            w[8*j+1] = 1.f - 2.f * f0.y;
                            w[8*j+2] = 1.f - 2.f * f1.x;
                            w[8*j+3] = 1.f - 2.f * f1.y;
                            w[8*j+4] = 1.f - 2.f * f2.x;
                            w[8*j+5] = 1.f - 2.f * f2.y;
                            w[8*j+6] = 1.f - 2.f * f3.x;
                            w[8*j+7] = 1.f - 2.f * f3.y;
                        }
                    }
                }
            }
            float a[8];
#pragma unroll
            for (int j = 0; j < 8; ++j) {
                float acc = 0.f;
#pragma unroll
                for (int k = 0; k < 17; ++k) acc += GWc[k] * w[j + k];
                a[j] = acc;
            }
            H8 o;
            o.a = __floats2half2_rn(a[0], a[1]);
            o.b = __floats2half2_rn(a[2], a[3]);
            o.c = __floats2half2_rn(a[4], a[5]);
            o.d = __floats2half2_rn(a[6], a[7]);
            *reinterpret_cast<H8*>(&sTmp[r * TILE + ci * 8]) = o;
        }
    }
    __syncthreads();

    // ===== vpass (round-5 verbatim) + pointwise epilogue =====
    const int cc = t & 63;
    const int rg = t >> 6;                 // 4 row groups x 16 rows
    const size_t pbase = ibase + (size_t)(row0 + rg * 16) * HW + (col0 + cc);

    float win[32];
#pragma unroll
    for (int j = 0; j < 32; ++j)
        win[j] = __half2float(sTmp[(rg * 16 + j) * TILE + cc]);

#pragma unroll
    for (int m = 0; m < 16; ++m) {
        float acc = 0.f;
#pragma unroll
        for (int k = 0; k < 17; ++k) acc += GWc[k] * win[m + k];

        size_t gidx = pbase + (size_t)m * HW;
        if constexpr (MODE == 0) {
            float xv  = xg[gidx];
            float lam = 100.f * inv1pexp(-10.f * cgl[gidx]);  // 100*sig(10c)
            xl[gidx] = __floats2half2_rn(xv, lam);
            ((__half*)uout)[gidx] = __float2half(inv1pexp(lam * acc * 0.1f));
        } else {
            float2 p = __half22float2(xl[gidx]);              // (x, lam)
            float uprev = __half2float(uin[gidx]);            // L2-hot
            float tt = (uprev - p.x) * 10.f + p.y * acc;      // (u-x)/tau+lam*v
            float uu = inv1pexp(tt * 0.1f);                   // sigmoid(-tt/eps)
            float res = 0.5f * uprev + 0.5f * uu;             // alpha = 0.5
            if constexpr (MODE == 2) ((float*)uout)[gidx] = res;
            else                     ((__half*)uout)[gidx] = __float2half(res);
        }
    }
}

extern "C" void kernel_launch(void* const* d_in, const int* in_sizes, int n_in,
                              void* d_out, int out_size, void* d_ws, size_t ws_size,
                              hipStream_t stream) {
    const float* x = (const float*)d_in[0];
    const float* c = (const float*)d_in[1];

    __half* u0 = (__half*)d_ws;          // NPIX halfs = 12.6 MB
    __half* u1 = u0 + NPIX;              // 12.6 MB
    __half2* xl = (ws_size >= NPIX * 8)
        ? (__half2*)((char*)d_ws + NPIX * 4)
        : (__half2*)d_out;               // safe: per-pixel read-before-write

    dim3 grid(HW / TILE, HW / TILE, NIMG);   // 8 x 8 x 24
    dim3 block(256);
    sig_step<0><<<grid, block, 0, stream>>>(x, c, nullptr, xl, u0);
    sig_step<1><<<grid, block, 0, stream>>>(x, c, u0, xl, u1);
    sig_step<1><<<grid, block, 0, stream>>>(x, c, u1, xl, u0);
    sig_step<1><<<grid, block, 0, stream>>>(x, c, u0, xl, u1);
    sig_step<1><<<grid, block, 0, stream>>>(x, c, u1, xl, u0);
    sig_step<2><<<grid, block, 0, stream>>>(x, c, u0, xl, d_out);
}